// Round 12
// baseline (727.819 us; speedup 1.0000x reference)
//
#include <hip/hip_runtime.h>

// GraphSAGE 3-layer + BN(train stats) + ReLU + classifier, MI355X.
// R10: baseline 797.85 us.
// R12: gathers MLP-insensitive. R15: FAILED fat-block fusion (TLP loss).
// R18: 781.98 tail-fill (kept). R19: 766.97 cls_fused. R20: FAILED (+21)
//      half-col split = 2x per-edge instructions -> request-rate evidence.
// R21: 688.75 VERIFIED. bucket_offsets 90us serial scan -> parallel
//      (prep0 totals + scan_buckets + bucket_prefix).
// R22: gathers: HALVE per-edge VMEM instructions. 16B/lane (VEC=4) or
//      8B/lane (VEC=2), lanes 0-31 = edge e, lanes 32-63 = edge e+1 ->
//      one instruction covers TWO rows. Partials combined via __shfl,
//      lanes 0-31 write. Bytes identical, 4 rows in flight kept.
//      Discriminates request-rate vs line-fetch bound; predicted
//      agg_mean<4> 111 -> 65-80us if request-bound.

#define DEV static __device__ __forceinline__

typedef unsigned short us;
typedef __attribute__((ext_vector_type(8))) __bf16 bf16x8;
typedef __attribute__((ext_vector_type(4))) float f32x4;

DEV float bf2f(us u) { return __uint_as_float(((unsigned)u) << 16); }
DEV us f2bf(float f) {
    unsigned u = __float_as_uint(f);
    unsigned r = u + 0x7fffu + ((u >> 16) & 1u);  // round-nearest-even
    return (us)(r >> 16);
}
DEV unsigned pack2(us a, us b) { return (unsigned)a | ((unsigned)b << 16); }

typedef __attribute__((address_space(3))) void lds_void;
typedef const __attribute__((address_space(1))) void gbl_void;
DEV void gll16(const void* g, void* l) {
    __builtin_amdgcn_global_load_lds((gbl_void*)g, (lds_void*)l, 16, 0, 0);
}

DEV bool is_i64(const int* ei) {
    return (ei[1] == 0) & (ei[3] == 0) & (ei[5] == 0) & (ei[7] == 0);
}

DEV void acc4(float* a, uint2 u) {  // 4 bf16 cols
    a[0] += __uint_as_float(u.x << 16);
    a[1] += __uint_as_float(u.x & 0xffff0000u);
    a[2] += __uint_as_float(u.y << 16);
    a[3] += __uint_as_float(u.y & 0xffff0000u);
}
DEV void acc8(float* a, uint4 u) {  // 8 bf16 cols
    a[0] += __uint_as_float(u.x << 16);
    a[1] += __uint_as_float(u.x & 0xffff0000u);
    a[2] += __uint_as_float(u.y << 16);
    a[3] += __uint_as_float(u.y & 0xffff0000u);
    a[4] += __uint_as_float(u.z << 16);
    a[5] += __uint_as_float(u.z & 0xffff0000u);
    a[6] += __uint_as_float(u.w << 16);
    a[7] += __uint_as_float(u.w & 0xffff0000u);
}

// ---------------- f32 -> bf16 conversion segments ----------------

struct WSeg { const float* s; us* d; int n4; int l2w4; int stride; };
struct WConvAll { WSeg seg[8]; };

// ---------------- prep0: bucket_hist (blocks 0..255) + conv (256..1279) ----

__global__ void prep0(WConvAll wc, const int* __restrict__ ei, int E,
                      int* __restrict__ hist2, int* __restrict__ totg,
                      int NB, int chunk) {
    __shared__ int h[256];
    const int t = threadIdx.x;
    if (blockIdx.x < 256) {
        const int g = blockIdx.x;
        const bool i64 = is_i64(ei);
        h[t] = 0;
        __syncthreads();
        int beg = g * chunk, end = min(beg + chunk, E);
        for (int e = beg + t; e < end; e += 256) {
            int d = i64 ? ei[2 * (E + e)] : ei[E + e];
            atomicAdd(&h[d >> 9], 1);
        }
        __syncthreads();
        if (t < NB) {
            hist2[g * NB + t] = h[t];
            if (h[t]) atomicAdd(&totg[t], h[t]);
        }
    } else {
        const int bid = blockIdx.x - 256;
        for (int sg = 0; sg < 8; ++sg) {
            WSeg w = wc.seg[sg];
            for (int i = bid * 256 + t; i < w.n4; i += 1024 * 256) {
                float4 v = ((const float4*)w.s)[i];
                ushort4 r;
                r.x = f2bf(v.x); r.y = f2bf(v.y); r.z = f2bf(v.z); r.w = f2bf(v.w);
                int row = i >> w.l2w4;
                int col = (i - (row << w.l2w4)) * 4;
                *(ushort4*)(w.d + (size_t)row * w.stride + col) = r;
            }
        }
    }
}

// ---------------- CSR build: parallel bucket scan (R21) ----------------

__global__ void scan_buckets(const int* __restrict__ totg, int* __restrict__ bucketBase,
                             int* __restrict__ rp, int N, int NB) {
    __shared__ int tot[256];
    const int t = threadIdx.x;
    int s = (t < NB) ? totg[t] : 0;
    tot[t] = s;
    __syncthreads();
    for (int off = 1; off < 256; off <<= 1) {
        int v = (t >= off) ? tot[t - off] : 0;
        __syncthreads();
        tot[t] += v;
        __syncthreads();
    }
    if (t < NB) {
        bucketBase[t] = tot[t] - s;
        if (t == NB - 1) {
            bucketBase[NB] = tot[t];
            rp[N] = tot[t];
        }
    }
}

__global__ void bucket_prefix(int* __restrict__ hist2, const int* __restrict__ bucketBase,
                              int NB) {
    __shared__ int sc[256];
    const int b = blockIdx.x;   // bucket
    const int t = threadIdx.x;  // chunk index g
    int v = hist2[t * NB + b];
    sc[t] = v;
    __syncthreads();
    for (int off = 1; off < 256; off <<= 1) {
        int x = (t >= off) ? sc[t - off] : 0;
        __syncthreads();
        sc[t] += x;
        __syncthreads();
    }
    hist2[t * NB + b] = bucketBase[b] + sc[t] - v;  // exclusive prefix + base
}

__global__ void scatter8(const int* __restrict__ ei, int E, const int* __restrict__ hist2,
                         uint2* __restrict__ ebuf, int NB, int chunk) {
    __shared__ int off[256];
    const int g = blockIdx.x, t = threadIdx.x;
    const bool i64 = is_i64(ei);
    if (t < NB) off[t] = hist2[g * NB + t];
    __syncthreads();
    int beg = g * chunk, end = min(beg + chunk, E);
    for (int e = beg + t; e < end; e += 256) {
        int s = i64 ? ei[2 * e] : ei[e];
        int d = i64 ? ei[2 * (E + e)] : ei[E + e];
        int p = atomicAdd(&off[d >> 9], 1);
        ebuf[p] = make_uint2((unsigned)s, (unsigned)d);
    }
}

__global__ void fine_csr(const uint2* __restrict__ ebuf, const int* __restrict__ bucketBase,
                         int N, int* __restrict__ rp, int* __restrict__ csr) {
    __shared__ int cnt[512];
    __shared__ int red[256];
    const int b = blockIdx.x, t = threadIdx.x;
    const int node0 = b << 9;
    cnt[t] = 0;
    cnt[t + 256] = 0;
    __syncthreads();
    const int ebeg = bucketBase[b], eend = bucketBase[b + 1];
    for (int e = ebeg + t; e < eend; e += 256) {
        uint2 r = ebuf[e];
        atomicAdd(&cnt[r.y & 511], 1);
    }
    __syncthreads();
    int c0 = cnt[2 * t], c1 = cnt[2 * t + 1];
    int s = c0 + c1;
    red[t] = s;
    __syncthreads();
    for (int off = 1; off < 256; off <<= 1) {
        int v = (t >= off) ? red[t - off] : 0;
        __syncthreads();
        red[t] += v;
        __syncthreads();
    }
    int pre = red[t] - s;
    int n0 = node0 + 2 * t;
    if (n0 < N) rp[n0] = ebeg + pre;
    if (n0 + 1 < N) rp[n0 + 1] = ebeg + pre + c0;
    __syncthreads();
    cnt[2 * t] = ebeg + pre;
    cnt[2 * t + 1] = ebeg + pre + c0;
    __syncthreads();
    for (int e = ebeg + t; e < eend; e += 256) {
        uint2 r = ebuf[e];
        int p = atomicAdd(&cnt[r.y & 511], 1);
        csr[p] = (int)r.x;
    }
}

// ---------------- mean aggregation: wide loads, 2 rows per instruction ----
// Lane covers 2*VEC cols (4*VEC bytes); lanes 0-31 = even edges, 32-63 = odd.
// One VMEM instruction fetches TWO rows -> per-edge request count halved.

template <int VEC>  // row cols = 64*VEC
__global__ void agg_mean(const us* __restrict__ X, const int* __restrict__ rp,
                         const int* __restrict__ csr, us* __restrict__ M, int n) {
    const int cols = VEC * 64;
    int w = blockIdx.x * (blockDim.x >> 6) + (threadIdx.x >> 6);
    int lane = threadIdx.x & 63;
    if (w >= n) return;
    int beg = rp[w], end = rp[w + 1];
    int cnt = end - beg;
    const int half = lane >> 5, hl = lane & 31;
    const us* Xb = X + hl * (2 * VEC);
    float acc[2 * VEC];
#pragma unroll
    for (int i = 0; i < 2 * VEC; ++i) acc[i] = 0.f;
    const int P = (cnt + 1) >> 1;

    if (VEC == 2) {
        uint2 uA, uB;
        bool vA = false, vB = false;
        auto ld = [&](int p, uint2& u, bool& v) {
            int idx = beg + 2 * p + half;
            v = idx < end;
            int j = v ? csr[idx] : csr[beg];
            u = *(const uint2*)(Xb + (size_t)j * cols);
        };
        if (P >= 2) {
            ld(0, uA, vA);
            ld(1, uB, vB);
            for (int p = 2; p < P; ++p) {
                uint2 uT; bool vT;
                ld(p, uT, vT);
                if (vA) acc4(acc, uA);
                uA = uB; vA = vB; uB = uT; vB = vT;
            }
            if (vA) acc4(acc, uA);
            if (vB) acc4(acc, uB);
        } else if (P == 1) {
            ld(0, uA, vA);
            if (vA) acc4(acc, uA);
        }
    } else {
        uint4 uA, uB;
        bool vA = false, vB = false;
        auto ld = [&](int p, uint4& u, bool& v) {
            int idx = beg + 2 * p + half;
            v = idx < end;
            int j = v ? csr[idx] : csr[beg];
            u = *(const uint4*)(Xb + (size_t)j * cols);
        };
        if (P >= 2) {
            ld(0, uA, vA);
            ld(1, uB, vB);
            for (int p = 2; p < P; ++p) {
                uint4 uT; bool vT;
                ld(p, uT, vT);
                if (vA) acc8(acc, uA);
                uA = uB; vA = vB; uB = uT; vB = vT;
            }
            if (vA) acc8(acc, uA);
            if (vB) acc8(acc, uB);
        } else if (P == 1) {
            ld(0, uA, vA);
            if (vA) acc8(acc, uA);
        }
    }

    float inv = 1.0f / (float)max(cnt, 1);
    us ov[2 * VEC];
#pragma unroll
    for (int i = 0; i < 2 * VEC; ++i) {
        float tot = acc[i] + __shfl(acc[i], hl + 32, 64);
        ov[i] = f2bf(tot * inv);
    }
    if (half == 0) {
        us* q = M + (size_t)w * cols + hl * (2 * VEC);
        if (VEC == 2) {
            *(uint2*)q = make_uint2(pack2(ov[0], ov[1]), pack2(ov[2], ov[3]));
        } else {
            *(uint4*)q = make_uint4(pack2(ov[0], ov[1]), pack2(ov[2], ov[3]),
                                    pack2(ov[4], ov[5]), pack2(ov[6], ov[7]));
        }
    }
}

// layer-3 post-GEMM aggregation: same 2-rows-per-instruction scheme.
// Gathers cols 0..127 of 256-stride rows; lane covers 4 cols (8B).
__global__ void agg_post(const us* __restrict__ Yc, const int* __restrict__ rp,
                         const int* __restrict__ csr, const float* __restrict__ bias,
                         us* __restrict__ H, int n) {
    int w = blockIdx.x * (blockDim.x >> 6) + (threadIdx.x >> 6);
    int lane = threadIdx.x & 63;
    if (w >= n) return;
    int beg = rp[w], end = rp[w + 1];
    int cnt = end - beg;
    const int half = lane >> 5, hl = lane & 31;
    const us* Yb = Yc + hl * 4;
    float acc[4] = {0.f, 0.f, 0.f, 0.f};
    const int P = (cnt + 1) >> 1;
    {
        uint2 uA, uB;
        bool vA = false, vB = false;
        auto ld = [&](int p, uint2& u, bool& v) {
            int idx = beg + 2 * p + half;
            v = idx < end;
            int j = v ? csr[idx] : csr[beg];
            u = *(const uint2*)(Yb + (size_t)j * 256);
        };
        if (P >= 2) {
            ld(0, uA, vA);
            ld(1, uB, vB);
            for (int p = 2; p < P; ++p) {
                uint2 uT; bool vT;
                ld(p, uT, vT);
                if (vA) acc4(acc, uA);
                uA = uB; vA = vB; uB = uT; vB = vT;
            }
            if (vA) acc4(acc, uA);
            if (vB) acc4(acc, uB);
        } else if (P == 1) {
            ld(0, uA, vA);
            if (vA) acc4(acc, uA);
        }
    }
    float inv = 1.0f / (float)max(cnt, 1);
    float tot[4];
#pragma unroll
    for (int i = 0; i < 4; ++i) tot[i] = acc[i] + __shfl(acc[i], hl + 32, 64);
    if (half == 0) {
        uint2 uz = *(const uint2*)(Yc + (size_t)w * 256 + 128 + hl * 4);
        float4 bv = *(const float4*)(bias + hl * 4);
        float r0 = tot[0] * inv + __uint_as_float(uz.x << 16) + bv.x;
        float r1 = tot[1] * inv + __uint_as_float(uz.x & 0xffff0000u) + bv.y;
        float r2 = tot[2] * inv + __uint_as_float(uz.y << 16) + bv.z;
        float r3 = tot[3] * inv + __uint_as_float(uz.y & 0xffff0000u) + bv.w;
        *(uint2*)(H + (size_t)w * 128 + hl * 4) =
            make_uint2(pack2(f2bf(r0), f2bf(r1)), pack2(f2bf(r2), f2bf(r3)));
    }
}

// ---------------- MFMA GEMM body: distance-2 DMA pipeline, dual LDS bufs ---
// NTE = per-wave col-tile count (4 = full BN, 2 = half-col remainder block).

template <int THREADS, int BM, int BN, int WM, int WN, int NTE>
DEV void gemm_body(const us* __restrict__ A0, int K0,
                   const us* __restrict__ A1, int K1,
                   const us* __restrict__ W, const float* __restrict__ bias,
                   int n, int outc, us* __restrict__ Cbf, float* __restrict__ Cf,
                   float* __restrict__ st0, float* __restrict__ st1,
                   int tile, int cbase,
                   us (*As)[BM * 32], us (*Bs)[BN * 32], float (*colred)[BN]) {
    constexpr int MT = WM / 16;
    constexpr int WCols = BN / WN;
    constexpr int BCB = WCols * NTE;                       // B col-blocks staged
    constexpr int NDMA = (BM * 4 + BCB * 64) / THREADS;    // DMA instrs/thread/tile
    static_assert((BM * 4) % THREADS == 0 && (BCB * 64) % THREADS == 0, "uniform DMA");

    const int t = threadIdx.x;
    const int wid = t >> 6, lane = t & 63;
    const int wr = wid / WCols, wcc = wid % WCols;
    const int row0 = tile * BM;
    const int Kp = K0 + K1;
    const int nk = Kp >> 5;
    const int l15 = lane & 15, l4 = lane >> 4;

    auto issue = [&](int kidx, int p) {
        int kc = kidx << 5;
        const us* A = (kc < K0) ? A0 : A1;
        int rs = (kc < K0) ? K0 : K1;
        int ko = (kc < K0) ? kc : kc - K0;
#pragma unroll
        for (int c = t; c < BM * 4; c += THREADS) {
            int blk = c >> 6;
            int row = row0 + (blk << 4) + l15;
            gll16(A + (size_t)row * rs + ko + (l4 << 3), (char*)As[p] + blk * 1024 + lane * 16);
        }
#pragma unroll
        for (int c = t; c < BCB * 64; c += THREADS) {
            int blk = c >> 6;
            int col = cbase + (blk << 4) + l15;
            gll16(W + (size_t)col * Kp + kc + (l4 << 3), (char*)Bs[p] + blk * 1024 + lane * 16);
        }
    };

    f32x4 acc[MT][NTE];
#pragma unroll
    for (int i = 0; i < MT; ++i)
#pragma unroll
        for (int j = 0; j < NTE; ++j) acc[i][j] = (f32x4){0.f, 0.f, 0.f, 0.f};

    issue(0, 0);
    if (nk > 1) issue(1, 1);
    for (int k = 0; k < nk; ++k) {
        // retire tile k's DMAs only; tile k+1 stays in flight
        if (k + 1 < nk) asm volatile("s_waitcnt vmcnt(%0)" :: "i"(NDMA) : "memory");
        else            asm volatile("s_waitcnt vmcnt(0)" ::: "memory");
        asm volatile("s_barrier" ::: "memory");
        const int p = k & 1;
        bf16x8 af[MT], bfr[NTE];
#pragma unroll
        for (int mt = 0; mt < MT; ++mt)
            af[mt] = *(const bf16x8*)((char*)As[p] + (wr * MT + mt) * 1024 + lane * 16);
#pragma unroll
        for (int nt = 0; nt < NTE; ++nt)
            bfr[nt] = *(const bf16x8*)((char*)Bs[p] + (wcc * NTE + nt) * 1024 + lane * 16);
#pragma unroll
        for (int mt = 0; mt < MT; ++mt)
#pragma unroll
            for (int nt = 0; nt < NTE; ++nt)
                acc[mt][nt] = __builtin_amdgcn_mfma_f32_16x16x32_bf16(af[mt], bfr[nt], acc[mt][nt], 0, 0, 0);
        if (k + 2 < nk) {
            asm volatile("s_barrier" ::: "memory");  // all waves done reading buf p
            issue(k + 2, p);
        }
    }

    if (st0) {
#pragma unroll
        for (int c = t; c < 2 * BN; c += THREADS) (&colred[0][0])[c] = 0.f;
        __syncthreads();
    }

    // epilogue: C/D map col=lane&15, row=(lane>>4)*4+reg
#pragma unroll
    for (int nt = 0; nt < NTE; ++nt) {
        int col = cbase + wcc * (NTE * 16) + nt * 16 + l15;
        bool cok = col < outc;
        float bv = (bias != nullptr && cok) ? bias[col] : 0.f;
        float ls = 0.f, lq = 0.f;
#pragma unroll
        for (int mt = 0; mt < MT; ++mt) {
            int rbase = row0 + wr * WM + mt * 16 + (l4 << 2);
#pragma unroll
            for (int i = 0; i < 4; ++i) {
                int r = rbase + i;
                if (r < n && cok) {
                    float v = acc[mt][nt][i] + bv;
                    if (Cf) Cf[(size_t)r * outc + col] = v;
                    else Cbf[(size_t)r * outc + col] = f2bf(v);
                    ls += v;
                    lq += v * v;
                }
            }
        }
        if (st0 && cok) {
            atomicAdd(&colred[0][col], ls);
            atomicAdd(&colred[1][col], lq);
        }
    }
    if (st0) {
        __syncthreads();
        int rep = (blockIdx.x & 7) << 8;  // 8-way replicated accumulators
        for (int c = t; c < BN; c += THREADS) {
            if (c < outc) {
                atomicAdd(&st0[rep + c], colred[0][c]);
                atomicAdd(&st1[rep + c], colred[1][c]);
            }
        }
    }
}

// Kernel wrapper: blocks [0,nFull) = full-width tiles; blocks >= nFull are
// half-column remainder blocks (2 per tile) that fill the dispatch tail.
template <int THREADS, int BM, int BN, int WM, int WN>
__launch_bounds__(THREADS)
__global__ void gemm_mfma(const us* __restrict__ A0, int K0,
                          const us* __restrict__ A1, int K1,
                          const us* __restrict__ W, const float* __restrict__ bias,
                          int n, int outc, us* __restrict__ Cbf, float* __restrict__ Cf,
                          float* __restrict__ st0, float* __restrict__ st1, int nFull) {
    static_assert((BM / WM) * (BN / WN) == THREADS / 64, "wave tiling");
    __shared__ __align__(16) us As[2][BM * 32];
    __shared__ __align__(16) us Bs[2][BN * 32];
    __shared__ float colred[2][BN];
    if ((int)blockIdx.x < nFull) {
        gemm_body<THREADS, BM, BN, WM, WN, WN / 16>(
            A0, K0, A1, K1, W, bias, n, outc, Cbf, Cf, st0, st1,
            blockIdx.x, 0, As, Bs, colred);
    } else if constexpr (BN == 256 && (WN / 16) % 2 == 0) {
        int idx = blockIdx.x - nFull;
        gemm_body<THREADS, BM, BN, WM, WN, WN / 32>(
            A0, K0, A1, K1, W, bias, n, outc, Cbf, Cf, st0, st1,
            nFull + (idx >> 1), (idx & 1) * (BN / 2), As, Bs, colred);
    }
}

// ---------------- BatchNorm ----------------

__global__ void bn_stats(const us* __restrict__ H, int n, int c,
                         float* __restrict__ s0, float* __restrict__ s1) {
    int col = threadIdx.x;
    if (col >= c) return;
    float s = 0.f, q = 0.f;
    for (int r = blockIdx.x; r < n; r += gridDim.x) {
        float v = bf2f(H[(size_t)r * c + col]);
        s += v;
        q += v * v;
    }
    int rep = (blockIdx.x & 7) << 8;
    atomicAdd(&s0[rep + col], s);
    atomicAdd(&s1[rep + col], q);
}

// bn_apply with inline finalize (sums `reps` stat replicas).
__global__ void bn_apply(us* __restrict__ H, int n8, int c,
                         const float* __restrict__ s0, const float* __restrict__ s1,
                         const float* __restrict__ g, const float* __restrict__ be, float fn,
                         int reps, int rstride) {
    __shared__ float sc[256], sh[256];
    int t = threadIdx.x;
    if (t < c) {
        float s = 0.f, q = 0.f;
        for (int r = 0; r < reps; ++r) {
            s += s0[r * rstride + t];
            q += s1[r * rstride + t];
        }
        float mean = s / fn;
        float var = q / fn - mean * mean;
        float scale = g[t] * rsqrtf(var + 1e-5f);
        sc[t] = scale;
        sh[t] = be[t] - mean * scale;
    }
    __syncthreads();
    const int cmask = (c >> 3) - 1;  // c/8 is pow2 (16 or 32): avoid runtime idiv
    for (int i = blockIdx.x * blockDim.x + t; i < n8; i += gridDim.x * blockDim.x) {
        int col = (i & cmask) << 3;
        uint4 v = ((const uint4*)H)[i];
        float f[8];
        f[0] = __uint_as_float(v.x << 16); f[1] = __uint_as_float(v.x & 0xffff0000u);
        f[2] = __uint_as_float(v.y << 16); f[3] = __uint_as_float(v.y & 0xffff0000u);
        f[4] = __uint_as_float(v.z << 16); f[5] = __uint_as_float(v.z & 0xffff0000u);
        f[6] = __uint_as_float(v.w << 16); f[7] = __uint_as_float(v.w & 0xffff0000u);
        float4 sc0 = *(const float4*)&sc[col];
        float4 sc1 = *(const float4*)&sc[col + 4];
        float4 sh0 = *(const float4*)&sh[col];
        float4 sh1 = *(const float4*)&sh[col + 4];
        f[0] = fmaxf(f[0] * sc0.x + sh0.x, 0.f);
        f[1] = fmaxf(f[1] * sc0.y + sh0.y, 0.f);
        f[2] = fmaxf(f[2] * sc0.z + sh0.z, 0.f);
        f[3] = fmaxf(f[3] * sc0.w + sh0.w, 0.f);
        f[4] = fmaxf(f[4] * sc1.x + sh1.x, 0.f);
        f[5] = fmaxf(f[5] * sc1.y + sh1.y, 0.f);
        f[6] = fmaxf(f[6] * sc1.z + sh1.z, 0.f);
        f[7] = fmaxf(f[7] * sc1.w + sh1.w, 0.f);
        uint4 o;
        o.x = (unsigned)f2bf(f[0]) | ((unsigned)f2bf(f[1]) << 16);
        o.y = (unsigned)f2bf(f[2]) | ((unsigned)f2bf(f[3]) << 16);
        o.z = (unsigned)f2bf(f[4]) | ((unsigned)f2bf(f[5]) << 16);
        o.w = (unsigned)f2bf(f[6]) | ((unsigned)f2bf(f[7]) << 16);
        ((uint4*)H)[i] = o;
    }
}

// ---------------- fused BN(L3)+ReLU+classifier ----------------

__global__ void cls_fused(const us* __restrict__ H,
                          const float* __restrict__ s0, const float* __restrict__ s1,
                          const float* __restrict__ g, const float* __restrict__ be,
                          const us* __restrict__ Wc, const float* __restrict__ bc,
                          float* __restrict__ out, int n, float fn) {
    __shared__ float sc[128], sh[128];
    const int t = threadIdx.x;
    if (t < 128) {
        float s = 0.f, q = 0.f;
#pragma unroll
        for (int r = 0; r < 8; ++r) {
            s += s0[(r << 8) + t];
            q += s1[(r << 8) + t];
        }
        float mean = s / fn;
        float var = q / fn - mean * mean;
        float scale = g[t] * rsqrtf(var + 1e-5f);
        sc[t] = scale;
        sh[t] = be[t] - mean * scale;
    }
    __syncthreads();

    const int lane = t & 63, wid = t >> 6;
    const int l15 = lane & 15, l4 = lane >> 4;
    bf16x8 bfr[4];
#pragma unroll
    for (int ks = 0; ks < 4; ++ks)
        bfr[ks] = *(const bf16x8*)(Wc + l15 * 128 + ks * 32 + (l4 << 3));
    const float bv = (l15 < 15) ? bc[l15] : 0.f;

    const int ntiles = (n + 15) >> 4;
    const int wstep = gridDim.x * (blockDim.x >> 6);
    for (int tile = blockIdx.x * (blockDim.x >> 6) + wid; tile < ntiles; tile += wstep) {
        const int arow = (tile << 4) + l15;
        f32x4 acc = (f32x4){0.f, 0.f, 0.f, 0.f};
#pragma unroll
        for (int ks = 0; ks < 4; ++ks) {
            const int kk = ks * 32 + (l4 << 3);
            uint4 o;
            if (arow < n) {
                uint4 v = *(const uint4*)(H + (size_t)arow * 128 + kk);
                float4 c0 = *(const float4*)&sc[kk];
                float4 c1 = *(const float4*)&sc[kk + 4];
                float4 h0 = *(const float4*)&sh[kk];
                float4 h1 = *(const float4*)&sh[kk + 4];
                float f0 = fmaxf(__uint_as_float(v.x << 16) * c0.x + h0.x, 0.f);
                float f1 = fmaxf(__uint_as_float(v.x & 0xffff0000u) * c0.y + h0.y, 0.f);
                float f2 = fmaxf(__uint_as_float(v.y << 16) * c0.z + h0.z, 0.f);
                float f3 = fmaxf(__uint_as_float(v.y & 0xffff0000u) * c0.w + h0.w, 0.f);
                float f4 = fmaxf(__uint_as_float(v.z << 16) * c1.x + h1.x, 0.f);
                float f5 = fmaxf(__uint_as_float(v.z & 0xffff0000u) * c1.y + h1.y, 0.f);
                float f6 = fmaxf(__uint_as_float(v.w << 16) * c1.z + h1.z, 0.f);
                float f7 = fmaxf(__uint_as_float(v.w & 0xffff0000u) * c1.w + h1.w, 0.f);
                o.x = (unsigned)f2bf(f0) | ((unsigned)f2bf(f1) << 16);
                o.y = (unsigned)f2bf(f2) | ((unsigned)f2bf(f3) << 16);
                o.z = (unsigned)f2bf(f4) | ((unsigned)f2bf(f5) << 16);
                o.w = (unsigned)f2bf(f6) | ((unsigned)f2bf(f7) << 16);
            } else {
                o.x = 0u; o.y = 0u; o.z = 0u; o.w = 0u;
            }
            acc = __builtin_amdgcn_mfma_f32_16x16x32_bf16(*(const bf16x8*)&o, bfr[ks], acc, 0, 0, 0);
        }
        if (l15 < 15) {
            const int rbase = (tile << 4) + (l4 << 2);
#pragma unroll
            for (int i = 0; i < 4; ++i) {
                int r = rbase + i;
                if (r < n) out[(size_t)r * 15 + l15] = acc[i] + bv;
            }
        }
    }
}

// ---------------- host ----------------

extern "C" void kernel_launch(void* const* d_in, const int* in_sizes, int n_in,
                              void* d_out, int out_size, void* d_ws, size_t ws_size,
                              hipStream_t stream) {
    const float* x = (const float*)d_in[0];
    const int* ei = (const int*)d_in[1];
    const float* w1_l = (const float*)d_in[2];
    const float* b1_l = (const float*)d_in[3];
    const float* w1_r = (const float*)d_in[4];
    const float* g1 = (const float*)d_in[5];
    const float* be1 = (const float*)d_in[6];
    const float* w2_l = (const float*)d_in[7];
    const float* b2_l = (const float*)d_in[8];
    const float* w2_r = (const float*)d_in[9];
    const float* g2 = (const float*)d_in[10];
    const float* be2 = (const float*)d_in[11];
    const float* w3_l = (const float*)d_in[12];
    const float* b3_l = (const float*)d_in[13];
    const float* w3_r = (const float*)d_in[14];
    const float* g3 = (const float*)d_in[15];
    const float* be3 = (const float*)d_in[16];
    const float* wcf = (const float*)d_in[17];
    const float* bc = (const float*)d_in[18];

    const int N = in_sizes[0] / 128;
    const int E = in_sizes[1] / 2;
    const int NB = (N + 511) >> 9;
    const int G = 256;
    const int chunk = (E + G - 1) / G;

    char* ws = (char*)d_ws;
    size_t off = 0;
    auto alloc = [&](size_t bytes) -> char* {
        char* p = ws + off;
        off += (bytes + 255) & ~(size_t)255;
        return p;
    };
    int* rp = (int*)alloc((size_t)(N + 1) * 4);
    int* csr = (int*)alloc((size_t)E * 4);
    int* hist2 = (int*)alloc((size_t)G * NB * 4);
    int* bucketBase = (int*)alloc((size_t)(NB + 1) * 4);
    int* totg = (int*)alloc(256 * 4);
    uint2* ebuf = (uint2*)alloc((size_t)E * 8);
    us* xbf = (us*)alloc((size_t)N * 128 * 2);
    us* M = (us*)alloc((size_t)N * 256 * 2);   // gather out / Yc
    us* Ha = (us*)alloc((size_t)N * 256 * 2);  // h1; later h3
    us* Hb = (us*)alloc((size_t)N * 256 * 2);  // h2
    float* stats = (float*)alloc(6 * 8 * 256 * 4);
    float* s01 = stats,          *s11 = stats + 2048;
    float* s02 = stats + 4096,   *s12 = stats + 6144;
    float* s03 = stats + 8192,   *s13 = stats + 10240;
    us* wcat1 = (us*)alloc(256 * 256 * 2);     // [256][128+128] = [w1_l | w1_r]
    us* wcat2 = (us*)alloc(256 * 512 * 2);     // [256][256+256] = [w2_l | w2_r]
    us* w3cat = (us*)alloc(256 * 256 * 2);     // rows 0-127 w3_l, 128-255 w3_r
    us* wc_b = (us*)alloc(64 * 128 * 2);       // 64 rows (rows 15-63 masked)
    alloc(1 << 20);                             // pad: absorbs OOB staging reads
    (void)ws_size; (void)n_in; (void)out_size;

    // --- conversions + CSR build + stat zero ---
    hipMemsetAsync(stats, 0, 6 * 8 * 256 * 4, stream);
    hipMemsetAsync(totg, 0, 256 * 4, stream);
    WConvAll wc;
    wc.seg[0] = {x,    xbf,         N * 128 / 4,  5, 128};
    wc.seg[1] = {w1_l, wcat1,       256 * 128 / 4, 5, 256};
    wc.seg[2] = {w1_r, wcat1 + 128, 256 * 128 / 4, 5, 256};
    wc.seg[3] = {w2_l, wcat2,       256 * 256 / 4, 6, 512};
    wc.seg[4] = {w2_r, wcat2 + 256, 256 * 256 / 4, 6, 512};
    wc.seg[5] = {w3_l, w3cat,             128 * 256 / 4, 6, 256};
    wc.seg[6] = {w3_r, w3cat + 128 * 256, 128 * 256 / 4, 6, 256};
    wc.seg[7] = {wcf,  wc_b,        15 * 128 / 4,  5, 128};
    prep0<<<1280, 256, 0, stream>>>(wc, ei, E, hist2, totg, NB, chunk);
    scan_buckets<<<1, 256, 0, stream>>>(totg, bucketBase, rp, N, NB);
    bucket_prefix<<<NB, 256, 0, stream>>>(hist2, bucketBase, NB);
    scatter8<<<G, 256, 0, stream>>>(ei, E, hist2, ebuf, NB, chunk);
    fine_csr<<<NB, 256, 0, stream>>>(ebuf, bucketBase, N, rp, csr);

    const int aggGrid = (N + 3) / 4;
    const int rowTiles = (N + 127) / 128;
    // tail-fill: 768 = 256 CU x 3 blocks/CU co-resident for the 512-thr GEMM
    const int nFull = rowTiles > 768 ? 768 : rowTiles;
    const int rem = rowTiles - nFull;
    const int gemmGrid = nFull + 2 * rem;

    // --- layer 1: 128 -> 256 (stats fused) ---
    agg_mean<2><<<aggGrid, 256, 0, stream>>>(xbf, rp, csr, M, N);
    gemm_mfma<512, 128, 256, 64, 64><<<gemmGrid, 512, 0, stream>>>(
        M, 128, xbf, 128, wcat1, b1_l, N, 256, Ha, nullptr, s01, s11, nFull);
    bn_apply<<<2048, 256, 0, stream>>>(Ha, N * 256 / 8, 256, s01, s11, g1, be1, (float)N, 8, 256);

    // --- layer 2: 256 -> 256 (stats fused) ---
    agg_mean<4><<<aggGrid, 256, 0, stream>>>(Ha, rp, csr, M, N);
    gemm_mfma<512, 128, 256, 64, 64><<<gemmGrid, 512, 0, stream>>>(
        M, 256, Ha, 256, wcat2, b2_l, N, 256, Hb, nullptr, s02, s12, nFull);
    bn_apply<<<2048, 256, 0, stream>>>(Hb, N * 256 / 8, 256, s02, s12, g2, be2, (float)N, 8, 256);

    // --- layer 3: GEMM-first: [Y|Z] = Hb @ [w3l;w3r]^T, aggregate 128 cols ---
    gemm_mfma<512, 128, 256, 64, 64><<<gemmGrid, 512, 0, stream>>>(
        Hb, 256, nullptr, 0, w3cat, nullptr, N, 256, M, nullptr, nullptr, nullptr, nFull);
    agg_post<<<aggGrid, 256, 0, stream>>>(M, rp, csr, b3_l, Ha, N);
    bn_stats<<<1024, 256, 0, stream>>>(Ha, N, 128, s03, s13);

    // --- fused BN(L3)+ReLU+classifier: 128 -> 15 (f32 out) ---
    cls_fused<<<1024, 256, 0, stream>>>(Ha, s03, s13, g3, be3, wc_b, bc,
                                        (float*)d_out, N, (float)N);
}

// Round 13
// 686.241 us; speedup vs baseline: 1.0606x; 1.0606x over previous
//
#include <hip/hip_runtime.h>

// GraphSAGE 3-layer + BN(train stats) + ReLU + classifier, MI355X.
// R10: baseline 797.85 us.
// R12: gathers MLP-insensitive. R15: FAILED fat-block fusion (TLP loss).
// R18: 781.98 tail-fill (kept). R19: 766.97 cls_fused.
// R20: FAILED (+21): 2x per-edge instructions.
// R21: 688.75 VERIFIED. bucket_offsets 90us serial -> parallel scan.
// R22: FAILED (+39): 0.5x per-edge instructions (2 rows/instr + shfl).
//      GATHERS CLOSED: +instr and -instr BOTH regress; 1-row/instr 8B/lane
//      is the optimum; bound by L2/EA random-line service (~54% hit).
// R23: revert to R21 gathers; merge scan_buckets into bucket_prefix
//      (every block redundantly scans the 196-entry totals in LDS;
//      block0 writes bucketBase[NB]/rp[N]) -> one fewer launch.

#define DEV static __device__ __forceinline__

typedef unsigned short us;
typedef __attribute__((ext_vector_type(8))) __bf16 bf16x8;
typedef __attribute__((ext_vector_type(4))) float f32x4;

DEV float bf2f(us u) { return __uint_as_float(((unsigned)u) << 16); }
DEV us f2bf(float f) {
    unsigned u = __float_as_uint(f);
    unsigned r = u + 0x7fffu + ((u >> 16) & 1u);  // round-nearest-even
    return (us)(r >> 16);
}

typedef __attribute__((address_space(3))) void lds_void;
typedef const __attribute__((address_space(1))) void gbl_void;
DEV void gll16(const void* g, void* l) {
    __builtin_amdgcn_global_load_lds((gbl_void*)g, (lds_void*)l, 16, 0, 0);
}

DEV bool is_i64(const int* ei) {
    return (ei[1] == 0) & (ei[3] == 0) & (ei[5] == 0) & (ei[7] == 0);
}

DEV void rowacc2(float* acc, unsigned u) {
    acc[0] += __uint_as_float(u << 16);
    acc[1] += __uint_as_float(u & 0xffff0000u);
}
DEV void rowacc4(float* acc, uint2 u) {
    acc[0] += __uint_as_float(u.x << 16);
    acc[1] += __uint_as_float(u.x & 0xffff0000u);
    acc[2] += __uint_as_float(u.y << 16);
    acc[3] += __uint_as_float(u.y & 0xffff0000u);
}

// ---------------- f32 -> bf16 conversion segments ----------------

struct WSeg { const float* s; us* d; int n4; int l2w4; int stride; };
struct WConvAll { WSeg seg[8]; };

// ---------------- prep0: bucket_hist (blocks 0..255) + conv (256..1279) ----
// hist blocks also accumulate per-bucket totals into totg (R21).

__global__ void prep0(WConvAll wc, const int* __restrict__ ei, int E,
                      int* __restrict__ hist2, int* __restrict__ totg,
                      int NB, int chunk) {
    __shared__ int h[256];
    const int t = threadIdx.x;
    if (blockIdx.x < 256) {
        const int g = blockIdx.x;
        const bool i64 = is_i64(ei);
        h[t] = 0;
        __syncthreads();
        int beg = g * chunk, end = min(beg + chunk, E);
        for (int e = beg + t; e < end; e += 256) {
            int d = i64 ? ei[2 * (E + e)] : ei[E + e];
            atomicAdd(&h[d >> 9], 1);
        }
        __syncthreads();
        if (t < NB) {
            hist2[g * NB + t] = h[t];
            if (h[t]) atomicAdd(&totg[t], h[t]);
        }
    } else {
        const int bid = blockIdx.x - 256;
        for (int sg = 0; sg < 8; ++sg) {
            WSeg w = wc.seg[sg];
            for (int i = bid * 256 + t; i < w.n4; i += 1024 * 256) {
                float4 v = ((const float4*)w.s)[i];
                ushort4 r;
                r.x = f2bf(v.x); r.y = f2bf(v.y); r.z = f2bf(v.z); r.w = f2bf(v.w);
                int row = i >> w.l2w4;
                int col = (i - (row << w.l2w4)) * 4;
                *(ushort4*)(w.d + (size_t)row * w.stride + col) = r;
            }
        }
    }
}

// ---------------- CSR build: parallel bucket scan (R21/R23) ----------------
// Fused: each block scans the bucket totals (for its base) AND its own
// bucket's per-chunk counts. Block 0 additionally writes bucketBase[NB], rp[N].

__global__ void bucket_prefix(int* __restrict__ hist2, const int* __restrict__ totg,
                              int* __restrict__ bucketBase, int* __restrict__ rp,
                              int N, int NB) {
    __shared__ int tb[256];
    __shared__ int ob[256];
    __shared__ int sc[256];
    const int b = blockIdx.x;   // bucket
    const int t = threadIdx.x;  // chunk index g (phase 2) / bucket idx (phase 1)
    int s = (t < NB) ? totg[t] : 0;
    tb[t] = s;
    ob[t] = s;
    __syncthreads();
    for (int off = 1; off < 256; off <<= 1) {
        int v = (t >= off) ? tb[t - off] : 0;
        __syncthreads();
        tb[t] += v;
        __syncthreads();
    }
    if (b == 0) {
        if (t < NB) bucketBase[t] = tb[t] - ob[t];
        if (t == NB - 1) {
            bucketBase[NB] = tb[t];
            rp[N] = tb[t];
        }
    }
    const int base = tb[b] - ob[b];
    // phase 2: scan this bucket's 256 chunk counts
    int v = hist2[t * NB + b];
    sc[t] = v;
    __syncthreads();
    for (int off = 1; off < 256; off <<= 1) {
        int x = (t >= off) ? sc[t - off] : 0;
        __syncthreads();
        sc[t] += x;
        __syncthreads();
    }
    hist2[t * NB + b] = base + sc[t] - v;  // exclusive prefix + base
}

__global__ void scatter8(const int* __restrict__ ei, int E, const int* __restrict__ hist2,
                         uint2* __restrict__ ebuf, int NB, int chunk) {
    __shared__ int off[256];
    const int g = blockIdx.x, t = threadIdx.x;
    const bool i64 = is_i64(ei);
    if (t < NB) off[t] = hist2[g * NB + t];
    __syncthreads();
    int beg = g * chunk, end = min(beg + chunk, E);
    for (int e = beg + t; e < end; e += 256) {
        int s = i64 ? ei[2 * e] : ei[e];
        int d = i64 ? ei[2 * (E + e)] : ei[E + e];
        int p = atomicAdd(&off[d >> 9], 1);
        ebuf[p] = make_uint2((unsigned)s, (unsigned)d);
    }
}

__global__ void fine_csr(const uint2* __restrict__ ebuf, const int* __restrict__ bucketBase,
                         int N, int* __restrict__ rp, int* __restrict__ csr) {
    __shared__ int cnt[512];
    __shared__ int red[256];
    const int b = blockIdx.x, t = threadIdx.x;
    const int node0 = b << 9;
    cnt[t] = 0;
    cnt[t + 256] = 0;
    __syncthreads();
    const int ebeg = bucketBase[b], eend = bucketBase[b + 1];
    for (int e = ebeg + t; e < eend; e += 256) {
        uint2 r = ebuf[e];
        atomicAdd(&cnt[r.y & 511], 1);
    }
    __syncthreads();
    int c0 = cnt[2 * t], c1 = cnt[2 * t + 1];
    int s = c0 + c1;
    red[t] = s;
    __syncthreads();
    for (int off = 1; off < 256; off <<= 1) {
        int v = (t >= off) ? red[t - off] : 0;
        __syncthreads();
        red[t] += v;
        __syncthreads();
    }
    int pre = red[t] - s;
    int n0 = node0 + 2 * t;
    if (n0 < N) rp[n0] = ebeg + pre;
    if (n0 + 1 < N) rp[n0 + 1] = ebeg + pre + c0;
    __syncthreads();
    cnt[2 * t] = ebeg + pre;
    cnt[2 * t + 1] = ebeg + pre + c0;
    __syncthreads();
    for (int e = ebeg + t; e < eend; e += 256) {
        uint2 r = ebuf[e];
        int p = atomicAdd(&cnt[r.y & 511], 1);
        csr[p] = (int)r.x;
    }
}

// ---------------- mean aggregation (wave per node, sw-pipelined) -----------
// R22 lesson: this 1-row-per-instruction 8B/lane layout is the optimum;
// both doubling and halving per-edge instruction count regress.

template <int VEC>  // cols = 64*VEC
__global__ void agg_mean(const us* __restrict__ X, const int* __restrict__ rp,
                         const int* __restrict__ csr, us* __restrict__ M, int n) {
    const int cols = VEC * 64;
    int w = blockIdx.x * (blockDim.x >> 6) + (threadIdx.x >> 6);
    int lane = threadIdx.x & 63;
    if (w >= n) return;
    int beg = rp[w], end = rp[w + 1];
    const us* Xb = X + lane * VEC;
    float acc[VEC];
#pragma unroll
    for (int i = 0; i < VEC; ++i) acc[i] = 0.f;
    int e = beg;
    int cnt = end - beg;
    if (VEC == 2) {
        if (cnt >= 8) {
            int j[4];
            unsigned u[4], un[4];
#pragma unroll
            for (int q = 0; q < 4; ++q) j[q] = csr[e + q];
#pragma unroll
            for (int q = 0; q < 4; ++q) u[q] = *(const unsigned*)(Xb + (size_t)j[q] * cols);
            for (e = beg + 4; e + 4 <= end; e += 4) {
#pragma unroll
                for (int q = 0; q < 4; ++q) j[q] = csr[e + q];
#pragma unroll
                for (int q = 0; q < 4; ++q) un[q] = *(const unsigned*)(Xb + (size_t)j[q] * cols);
#pragma unroll
                for (int q = 0; q < 4; ++q) rowacc2(acc, u[q]);
#pragma unroll
                for (int q = 0; q < 4; ++q) u[q] = un[q];
            }
#pragma unroll
            for (int q = 0; q < 4; ++q) rowacc2(acc, u[q]);
        }
        for (; e < end; ++e) rowacc2(acc, *(const unsigned*)(Xb + (size_t)csr[e] * cols));
    } else {
        if (cnt >= 8) {
            int j[4];
            uint2 u[4], un[4];
#pragma unroll
            for (int q = 0; q < 4; ++q) j[q] = csr[e + q];
#pragma unroll
            for (int q = 0; q < 4; ++q) u[q] = *(const uint2*)(Xb + (size_t)j[q] * cols);
            for (e = beg + 4; e + 4 <= end; e += 4) {
#pragma unroll
                for (int q = 0; q < 4; ++q) j[q] = csr[e + q];
#pragma unroll
                for (int q = 0; q < 4; ++q) un[q] = *(const uint2*)(Xb + (size_t)j[q] * cols);
#pragma unroll
                for (int q = 0; q < 4; ++q) rowacc4(acc, u[q]);
#pragma unroll
                for (int q = 0; q < 4; ++q) u[q] = un[q];
            }
#pragma unroll
            for (int q = 0; q < 4; ++q) rowacc4(acc, u[q]);
        }
        for (; e < end; ++e) rowacc4(acc, *(const uint2*)(Xb + (size_t)csr[e] * cols));
    }
    float inv = 1.0f / (float)max(cnt, 1);
    us* q = M + (size_t)w * cols + lane * VEC;
    if (VEC == 2) {
        *(ushort2*)q = make_ushort2(f2bf(acc[0] * inv), f2bf(acc[1] * inv));
    } else {
        *(ushort4*)q = make_ushort4(f2bf(acc[0] * inv), f2bf(acc[1] * inv),
                                    f2bf(acc[2] * inv), f2bf(acc[3] * inv));
    }
}

// layer-3 post-GEMM aggregation, sw-pipelined, NO stats (R11 lesson).
__global__ void agg_post(const us* __restrict__ Yc, const int* __restrict__ rp,
                         const int* __restrict__ csr, const float* __restrict__ bias,
                         us* __restrict__ H, int n) {
    int w = blockIdx.x * (blockDim.x >> 6) + (threadIdx.x >> 6);
    int lane = threadIdx.x & 63;
    if (w >= n) return;
    int beg = rp[w], end = rp[w + 1];
    const us* Yb = Yc + lane * 2;
    float acc[2] = {0.f, 0.f};
    int e = beg;
    int cnt = end - beg;
    if (cnt >= 8) {
        int j[4];
        unsigned u[4], un[4];
#pragma unroll
        for (int q = 0; q < 4; ++q) j[q] = csr[e + q];
#pragma unroll
        for (int q = 0; q < 4; ++q) u[q] = *(const unsigned*)(Yb + (size_t)j[q] * 256);
        for (e = beg + 4; e + 4 <= end; e += 4) {
#pragma unroll
            for (int q = 0; q < 4; ++q) j[q] = csr[e + q];
#pragma unroll
            for (int q = 0; q < 4; ++q) un[q] = *(const unsigned*)(Yb + (size_t)j[q] * 256);
#pragma unroll
            for (int q = 0; q < 4; ++q) rowacc2(acc, u[q]);
#pragma unroll
            for (int q = 0; q < 4; ++q) u[q] = un[q];
        }
#pragma unroll
        for (int q = 0; q < 4; ++q) rowacc2(acc, u[q]);
    }
    for (; e < end; ++e) rowacc2(acc, *(const unsigned*)(Yb + (size_t)csr[e] * 256));
    float inv = 1.0f / (float)max(cnt, 1);
    unsigned uz = *(const unsigned*)(Yc + (size_t)w * 256 + 128 + lane * 2);
    float2 bv = *(const float2*)(bias + lane * 2);
    float r0 = acc[0] * inv + __uint_as_float(uz << 16) + bv.x;
    float r1 = acc[1] * inv + __uint_as_float(uz & 0xffff0000u) + bv.y;
    *(ushort2*)(H + (size_t)w * 128 + lane * 2) = make_ushort2(f2bf(r0), f2bf(r1));
}

// ---------------- MFMA GEMM body: distance-2 DMA pipeline, dual LDS bufs ---
// NTE = per-wave col-tile count (4 = full BN, 2 = half-col remainder block).

template <int THREADS, int BM, int BN, int WM, int WN, int NTE>
DEV void gemm_body(const us* __restrict__ A0, int K0,
                   const us* __restrict__ A1, int K1,
                   const us* __restrict__ W, const float* __restrict__ bias,
                   int n, int outc, us* __restrict__ Cbf, float* __restrict__ Cf,
                   float* __restrict__ st0, float* __restrict__ st1,
                   int tile, int cbase,
                   us (*As)[BM * 32], us (*Bs)[BN * 32], float (*colred)[BN]) {
    constexpr int MT = WM / 16;
    constexpr int WCols = BN / WN;
    constexpr int BCB = WCols * NTE;                       // B col-blocks staged
    constexpr int NDMA = (BM * 4 + BCB * 64) / THREADS;    // DMA instrs/thread/tile
    static_assert((BM * 4) % THREADS == 0 && (BCB * 64) % THREADS == 0, "uniform DMA");

    const int t = threadIdx.x;
    const int wid = t >> 6, lane = t & 63;
    const int wr = wid / WCols, wcc = wid % WCols;
    const int row0 = tile * BM;
    const int Kp = K0 + K1;
    const int nk = Kp >> 5;
    const int l15 = lane & 15, l4 = lane >> 4;

    auto issue = [&](int kidx, int p) {
        int kc = kidx << 5;
        const us* A = (kc < K0) ? A0 : A1;
        int rs = (kc < K0) ? K0 : K1;
        int ko = (kc < K0) ? kc : kc - K0;
#pragma unroll
        for (int c = t; c < BM * 4; c += THREADS) {
            int blk = c >> 6;
            int row = row0 + (blk << 4) + l15;
            gll16(A + (size_t)row * rs + ko + (l4 << 3), (char*)As[p] + blk * 1024 + lane * 16);
        }
#pragma unroll
        for (int c = t; c < BCB * 64; c += THREADS) {
            int blk = c >> 6;
            int col = cbase + (blk << 4) + l15;
            gll16(W + (size_t)col * Kp + kc + (l4 << 3), (char*)Bs[p] + blk * 1024 + lane * 16);
        }
    };

    f32x4 acc[MT][NTE];
#pragma unroll
    for (int i = 0; i < MT; ++i)
#pragma unroll
        for (int j = 0; j < NTE; ++j) acc[i][j] = (f32x4){0.f, 0.f, 0.f, 0.f};

    issue(0, 0);
    if (nk > 1) issue(1, 1);
    for (int k = 0; k < nk; ++k) {
        // retire tile k's DMAs only; tile k+1 stays in flight
        if (k + 1 < nk) asm volatile("s_waitcnt vmcnt(%0)" :: "i"(NDMA) : "memory");
        else            asm volatile("s_waitcnt vmcnt(0)" ::: "memory");
        asm volatile("s_barrier" ::: "memory");
        const int p = k & 1;
        bf16x8 af[MT], bfr[NTE];
#pragma unroll
        for (int mt = 0; mt < MT; ++mt)
            af[mt] = *(const bf16x8*)((char*)As[p] + (wr * MT + mt) * 1024 + lane * 16);
#pragma unroll
        for (int nt = 0; nt < NTE; ++nt)
            bfr[nt] = *(const bf16x8*)((char*)Bs[p] + (wcc * NTE + nt) * 1024 + lane * 16);
#pragma unroll
        for (int mt = 0; mt < MT; ++mt)
#pragma unroll
            for (int nt = 0; nt < NTE; ++nt)
                acc[mt][nt] = __builtin_amdgcn_mfma_f32_16x16x32_bf16(af[mt], bfr[nt], acc[mt][nt], 0, 0, 0);
        if (k + 2 < nk) {
            asm volatile("s_barrier" ::: "memory");  // all waves done reading buf p
            issue(k + 2, p);
        }
    }

    if (st0) {
#pragma unroll
        for (int c = t; c < 2 * BN; c += THREADS) (&colred[0][0])[c] = 0.f;
        __syncthreads();
    }

    // epilogue: C/D map col=lane&15, row=(lane>>4)*4+reg
#pragma unroll
    for (int nt = 0; nt < NTE; ++nt) {
        int col = cbase + wcc * (NTE * 16) + nt * 16 + l15;
        bool cok = col < outc;
        float bv = (bias != nullptr && cok) ? bias[col] : 0.f;
        float ls = 0.f, lq = 0.f;
#pragma unroll
        for (int mt = 0; mt < MT; ++mt) {
            int rbase = row0 + wr * WM + mt * 16 + (l4 << 2);
#pragma unroll
            for (int i = 0; i < 4; ++i) {
                int r = rbase + i;
                if (r < n && cok) {
                    float v = acc[mt][nt][i] + bv;
                    if (Cf) Cf[(size_t)r * outc + col] = v;
                    else Cbf[(size_t)r * outc + col] = f2bf(v);
                    ls += v;
                    lq += v * v;
                }
            }
        }
        if (st0 && cok) {
            atomicAdd(&colred[0][col], ls);
            atomicAdd(&colred[1][col], lq);
        }
    }
    if (st0) {
        __syncthreads();
        int rep = (blockIdx.x & 7) << 8;  // 8-way replicated accumulators
        for (int c = t; c < BN; c += THREADS) {
            if (c < outc) {
                atomicAdd(&st0[rep + c], colred[0][c]);
                atomicAdd(&st1[rep + c], colred[1][c]);
            }
        }
    }
}

// Kernel wrapper: blocks [0,nFull) = full-width tiles; blocks >= nFull are
// half-column remainder blocks (2 per tile) that fill the dispatch tail.
template <int THREADS, int BM, int BN, int WM, int WN>
__launch_bounds__(THREADS)
__global__ void gemm_mfma(const us* __restrict__ A0, int K0,
                          const us* __restrict__ A1, int K1,
                          const us* __restrict__ W, const float* __restrict__ bias,
                          int n, int outc, us* __restrict__ Cbf, float* __restrict__ Cf,
                          float* __restrict__ st0, float* __restrict__ st1, int nFull) {
    static_assert((BM / WM) * (BN / WN) == THREADS / 64, "wave tiling");
    __shared__ __align__(16) us As[2][BM * 32];
    __shared__ __align__(16) us Bs[2][BN * 32];
    __shared__ float colred[2][BN];
    if ((int)blockIdx.x < nFull) {
        gemm_body<THREADS, BM, BN, WM, WN, WN / 16>(
            A0, K0, A1, K1, W, bias, n, outc, Cbf, Cf, st0, st1,
            blockIdx.x, 0, As, Bs, colred);
    } else if constexpr (BN == 256 && (WN / 16) % 2 == 0) {
        int idx = blockIdx.x - nFull;
        gemm_body<THREADS, BM, BN, WM, WN, WN / 32>(
            A0, K0, A1, K1, W, bias, n, outc, Cbf, Cf, st0, st1,
            nFull + (idx >> 1), (idx & 1) * (BN / 2), As, Bs, colred);
    }
}

// ---------------- BatchNorm ----------------

__global__ void bn_stats(const us* __restrict__ H, int n, int c,
                         float* __restrict__ s0, float* __restrict__ s1) {
    int col = threadIdx.x;
    if (col >= c) return;
    float s = 0.f, q = 0.f;
    for (int r = blockIdx.x; r < n; r += gridDim.x) {
        float v = bf2f(H[(size_t)r * c + col]);
        s += v;
        q += v * v;
    }
    int rep = (blockIdx.x & 7) << 8;
    atomicAdd(&s0[rep + col], s);
    atomicAdd(&s1[rep + col], q);
}

// bn_apply with inline finalize (sums `reps` stat replicas).
__global__ void bn_apply(us* __restrict__ H, int n8, int c,
                         const float* __restrict__ s0, const float* __restrict__ s1,
                         const float* __restrict__ g, const float* __restrict__ be, float fn,
                         int reps, int rstride) {
    __shared__ float sc[256], sh[256];
    int t = threadIdx.x;
    if (t < c) {
        float s = 0.f, q = 0.f;
        for (int r = 0; r < reps; ++r) {
            s += s0[r * rstride + t];
            q += s1[r * rstride + t];
        }
        float mean = s / fn;
        float var = q / fn - mean * mean;
        float scale = g[t] * rsqrtf(var + 1e-5f);
        sc[t] = scale;
        sh[t] = be[t] - mean * scale;
    }
    __syncthreads();
    const int cmask = (c >> 3) - 1;  // c/8 is pow2 (16 or 32): avoid runtime idiv
    for (int i = blockIdx.x * blockDim.x + t; i < n8; i += gridDim.x * blockDim.x) {
        int col = (i & cmask) << 3;
        uint4 v = ((const uint4*)H)[i];
        float f[8];
        f[0] = __uint_as_float(v.x << 16); f[1] = __uint_as_float(v.x & 0xffff0000u);
        f[2] = __uint_as_float(v.y << 16); f[3] = __uint_as_float(v.y & 0xffff0000u);
        f[4] = __uint_as_float(v.z << 16); f[5] = __uint_as_float(v.z & 0xffff0000u);
        f[6] = __uint_as_float(v.w << 16); f[7] = __uint_as_float(v.w & 0xffff0000u);
        float4 sc0 = *(const float4*)&sc[col];
        float4 sc1 = *(const float4*)&sc[col + 4];
        float4 sh0 = *(const float4*)&sh[col];
        float4 sh1 = *(const float4*)&sh[col + 4];
        f[0] = fmaxf(f[0] * sc0.x + sh0.x, 0.f);
        f[1] = fmaxf(f[1] * sc0.y + sh0.y, 0.f);
        f[2] = fmaxf(f[2] * sc0.z + sh0.z, 0.f);
        f[3] = fmaxf(f[3] * sc0.w + sh0.w, 0.f);
        f[4] = fmaxf(f[4] * sc1.x + sh1.x, 0.f);
        f[5] = fmaxf(f[5] * sc1.y + sh1.y, 0.f);
        f[6] = fmaxf(f[6] * sc1.z + sh1.z, 0.f);
        f[7] = fmaxf(f[7] * sc1.w + sh1.w, 0.f);
        uint4 o;
        o.x = (unsigned)f2bf(f[0]) | ((unsigned)f2bf(f[1]) << 16);
        o.y = (unsigned)f2bf(f[2]) | ((unsigned)f2bf(f[3]) << 16);
        o.z = (unsigned)f2bf(f[4]) | ((unsigned)f2bf(f[5]) << 16);
        o.w = (unsigned)f2bf(f[6]) | ((unsigned)f2bf(f[7]) << 16);
        ((uint4*)H)[i] = o;
    }
}

// ---------------- fused BN(L3)+ReLU+classifier ----------------

__global__ void cls_fused(const us* __restrict__ H,
                          const float* __restrict__ s0, const float* __restrict__ s1,
                          const float* __restrict__ g, const float* __restrict__ be,
                          const us* __restrict__ Wc, const float* __restrict__ bc,
                          float* __restrict__ out, int n, float fn) {
    __shared__ float sc[128], sh[128];
    const int t = threadIdx.x;
    if (t < 128) {
        float s = 0.f, q = 0.f;
#pragma unroll
        for (int r = 0; r < 8; ++r) {
            s += s0[(r << 8) + t];
            q += s1[(r << 8) + t];
        }
        float mean = s / fn;
        float var = q / fn - mean * mean;
        float scale = g[t] * rsqrtf(var + 1e-5f);
        sc[t] = scale;
        sh[t] = be[t] - mean * scale;
    }
    __syncthreads();

    const int lane = t & 63, wid = t >> 6;
    const int l15 = lane & 15, l4 = lane >> 4;
    bf16x8 bfr[4];
#pragma unroll
    for (int ks = 0; ks < 4; ++ks)
        bfr[ks] = *(const bf16x8*)(Wc + l15 * 128 + ks * 32 + (l4 << 3));
    const float bv = (l15 < 15) ? bc[l15] : 0.f;

    const int ntiles = (n + 15) >> 4;
    const int wstep = gridDim.x * (blockDim.x >> 6);
    for (int tile = blockIdx.x * (blockDim.x >> 6) + wid; tile < ntiles; tile += wstep) {
        const int arow = (tile << 4) + l15;
        f32x4 acc = (f32x4){0.f, 0.f, 0.f, 0.f};
#pragma unroll
        for (int ks = 0; ks < 4; ++ks) {
            const int kk = ks * 32 + (l4 << 3);
            uint4 o;
            if (arow < n) {
                uint4 v = *(const uint4*)(H + (size_t)arow * 128 + kk);
                float4 c0 = *(const float4*)&sc[kk];
                float4 c1 = *(const float4*)&sc[kk + 4];
                float4 h0 = *(const float4*)&sh[kk];
                float4 h1 = *(const float4*)&sh[kk + 4];
                float f0 = fmaxf(__uint_as_float(v.x << 16) * c0.x + h0.x, 0.f);
                float f1 = fmaxf(__uint_as_float(v.x & 0xffff0000u) * c0.y + h0.y, 0.f);
                float f2 = fmaxf(__uint_as_float(v.y << 16) * c0.z + h0.z, 0.f);
                float f3 = fmaxf(__uint_as_float(v.y & 0xffff0000u) * c0.w + h0.w, 0.f);
                float f4 = fmaxf(__uint_as_float(v.z << 16) * c1.x + h1.x, 0.f);
                float f5 = fmaxf(__uint_as_float(v.z & 0xffff0000u) * c1.y + h1.y, 0.f);
                float f6 = fmaxf(__uint_as_float(v.w << 16) * c1.z + h1.z, 0.f);
                float f7 = fmaxf(__uint_as_float(v.w & 0xffff0000u) * c1.w + h1.w, 0.f);
                o.x = (unsigned)f2bf(f0) | ((unsigned)f2bf(f1) << 16);
                o.y = (unsigned)f2bf(f2) | ((unsigned)f2bf(f3) << 16);
                o.z = (unsigned)f2bf(f4) | ((unsigned)f2bf(f5) << 16);
                o.w = (unsigned)f2bf(f6) | ((unsigned)f2bf(f7) << 16);
            } else {
                o.x = 0u; o.y = 0u; o.z = 0u; o.w = 0u;
            }
            acc = __builtin_amdgcn_mfma_f32_16x16x32_bf16(*(const bf16x8*)&o, bfr[ks], acc, 0, 0, 0);
        }
        if (l15 < 15) {
            const int rbase = (tile << 4) + (l4 << 2);
#pragma unroll
            for (int i = 0; i < 4; ++i) {
                int r = rbase + i;
                if (r < n) out[(size_t)r * 15 + l15] = acc[i] + bv;
            }
        }
    }
}

// ---------------- host ----------------

extern "C" void kernel_launch(void* const* d_in, const int* in_sizes, int n_in,
                              void* d_out, int out_size, void* d_ws, size_t ws_size,
                              hipStream_t stream) {
    const float* x = (const float*)d_in[0];
    const int* ei = (const int*)d_in[1];
    const float* w1_l = (const float*)d_in[2];
    const float* b1_l = (const float*)d_in[3];
    const float* w1_r = (const float*)d_in[4];
    const float* g1 = (const float*)d_in[5];
    const float* be1 = (const float*)d_in[6];
    const float* w2_l = (const float*)d_in[7];
    const float* b2_l = (const float*)d_in[8];
    const float* w2_r = (const float*)d_in[9];
    const float* g2 = (const float*)d_in[10];
    const float* be2 = (const float*)d_in[11];
    const float* w3_l = (const float*)d_in[12];
    const float* b3_l = (const float*)d_in[13];
    const float* w3_r = (const float*)d_in[14];
    const float* g3 = (const float*)d_in[15];
    const float* be3 = (const float*)d_in[16];
    const float* wcf = (const float*)d_in[17];
    const float* bc = (const float*)d_in[18];

    const int N = in_sizes[0] / 128;
    const int E = in_sizes[1] / 2;
    const int NB = (N + 511) >> 9;
    const int G = 256;
    const int chunk = (E + G - 1) / G;

    char* ws = (char*)d_ws;
    size_t off = 0;
    auto alloc = [&](size_t bytes) -> char* {
        char* p = ws + off;
        off += (bytes + 255) & ~(size_t)255;
        return p;
    };
    int* rp = (int*)alloc((size_t)(N + 1) * 4);
    int* csr = (int*)alloc((size_t)E * 4);
    int* hist2 = (int*)alloc((size_t)G * NB * 4);
    int* bucketBase = (int*)alloc((size_t)(NB + 1) * 4);
    int* totg = (int*)alloc(256 * 4);
    uint2* ebuf = (uint2*)alloc((size_t)E * 8);
    us* xbf = (us*)alloc((size_t)N * 128 * 2);
    us* M = (us*)alloc((size_t)N * 256 * 2);   // gather out / Yc
    us* Ha = (us*)alloc((size_t)N * 256 * 2);  // h1; later h3
    us* Hb = (us*)alloc((size_t)N * 256 * 2);  // h2
    float* stats = (float*)alloc(6 * 8 * 256 * 4);
    float* s01 = stats,          *s11 = stats + 2048;
    float* s02 = stats + 4096,   *s12 = stats + 6144;
    float* s03 = stats + 8192,   *s13 = stats + 10240;
    us* wcat1 = (us*)alloc(256 * 256 * 2);     // [256][128+128] = [w1_l | w1_r]
    us* wcat2 = (us*)alloc(256 * 512 * 2);     // [256][256+256] = [w2_l | w2_r]
    us* w3cat = (us*)alloc(256 * 256 * 2);     // rows 0-127 w3_l, 128-255 w3_r
    us* wc_b = (us*)alloc(64 * 128 * 2);       // 64 rows (rows 15-63 masked)
    alloc(1 << 20);                             // pad: absorbs OOB staging reads
    (void)ws_size; (void)n_in; (void)out_size;

    // --- conversions + CSR build + stat zero ---
    hipMemsetAsync(stats, 0, 6 * 8 * 256 * 4, stream);
    hipMemsetAsync(totg, 0, 256 * 4, stream);
    WConvAll wc;
    wc.seg[0] = {x,    xbf,         N * 128 / 4,  5, 128};
    wc.seg[1] = {w1_l, wcat1,       256 * 128 / 4, 5, 256};
    wc.seg[2] = {w1_r, wcat1 + 128, 256 * 128 / 4, 5, 256};
    wc.seg[3] = {w2_l, wcat2,       256 * 256 / 4, 6, 512};
    wc.seg[4] = {w2_r, wcat2 + 256, 256 * 256 / 4, 6, 512};
    wc.seg[5] = {w3_l, w3cat,             128 * 256 / 4, 6, 256};
    wc.seg[6] = {w3_r, w3cat + 128 * 256, 128 * 256 / 4, 6, 256};
    wc.seg[7] = {wcf,  wc_b,        15 * 128 / 4,  5, 128};
    prep0<<<1280, 256, 0, stream>>>(wc, ei, E, hist2, totg, NB, chunk);
    bucket_prefix<<<NB, 256, 0, stream>>>(hist2, totg, bucketBase, rp, N, NB);
    scatter8<<<G, 256, 0, stream>>>(ei, E, hist2, ebuf, NB, chunk);
    fine_csr<<<NB, 256, 0, stream>>>(ebuf, bucketBase, N, rp, csr);

    const int aggGrid = (N + 3) / 4;
    const int rowTiles = (N + 127) / 128;
    // tail-fill: 768 = 256 CU x 3 blocks/CU co-resident for the 512-thr GEMM
    const int nFull = rowTiles > 768 ? 768 : rowTiles;
    const int rem = rowTiles - nFull;
    const int gemmGrid = nFull + 2 * rem;

    // --- layer 1: 128 -> 256 (stats fused) ---
    agg_mean<2><<<aggGrid, 256, 0, stream>>>(xbf, rp, csr, M, N);
    gemm_mfma<512, 128, 256, 64, 64><<<gemmGrid, 512, 0, stream>>>(
        M, 128, xbf, 128, wcat1, b1_l, N, 256, Ha, nullptr, s01, s11, nFull);
    bn_apply<<<2048, 256, 0, stream>>>(Ha, N * 256 / 8, 256, s01, s11, g1, be1, (float)N, 8, 256);

    // --- layer 2: 256 -> 256 (stats fused) ---
    agg_mean<4><<<aggGrid, 256, 0, stream>>>(Ha, rp, csr, M, N);
    gemm_mfma<512, 128, 256, 64, 64><<<gemmGrid, 512, 0, stream>>>(
        M, 256, Ha, 256, wcat2, b2_l, N, 256, Hb, nullptr, s02, s12, nFull);
    bn_apply<<<2048, 256, 0, stream>>>(Hb, N * 256 / 8, 256, s02, s12, g2, be2, (float)N, 8, 256);

    // --- layer 3: GEMM-first: [Y|Z] = Hb @ [w3l;w3r]^T, aggregate 128 cols ---
    gemm_mfma<512, 128, 256, 64, 64><<<gemmGrid, 512, 0, stream>>>(
        Hb, 256, nullptr, 0, w3cat, nullptr, N, 256, M, nullptr, nullptr, nullptr, nFull);
    agg_post<<<aggGrid, 256, 0, stream>>>(M, rp, csr, b3_l, Ha, N);
    bn_stats<<<1024, 256, 0, stream>>>(Ha, N, 128, s03, s13);

    // --- fused BN(L3)+ReLU+classifier: 128 -> 15 (f32 out) ---
    cls_fused<<<1024, 256, 0, stream>>>(Ha, s03, s13, g3, be3, wc_b, bc,
                                        (float*)d_out, N, (float)N);
}